// Round 4
// baseline (320.825 us; speedup 1.0000x reference)
//
#include <hip/hip_runtime.h>
#include <cstdint>

// Instant-NGP hash-grid embedder, 2-phase with level->XCD affinity.
//
// Journal:
//  R2: level->XCD affinity (blockIdx%8 pins level pairs (i,15-i)); FETCH
//      1.56GB -> 149MB. Phase A ~= per-XCD L2 request roofline.
//  R4: no __builtin_nontemporal_* (regressed both phases).
//  R5: phase-B store coalescing: NEUTRAL.  R6: chunk-major reads: NEUTRAL.
//  R7: fused tail transpose: FAILED (sc1 write-through doubled WRITE), but
//      measured harness overhead ~78us/iter => phase B true cost ~33us
//      ~= its 128MB roofline. Phase B is DONE. Budget = phase A only.
//  R8: parity-paired x-corners (x hash prime = 1 -> idx(i0+1)=idx(i0)^1 for
//      even i0; pair = one aligned float4). Requests -25%, phase A
//      225->199us (-11.6% only). Amdahl fit: request component ~104us,
//      residual ~95us. Suspect: divergence made every wave issue 12 gather
//      instrs (4 masked-even + 8 masked-odd) vs 8 before — per-instruction
//      VMEM front-end cost co-limits.
//  R9 (this): PARITY COMPACTION. Ballot+scan partitions the block's 256
//      points into even/odd slots via LDS; gather waves run parity-uniform
//      (4 instrs even-wave / 8 odd-wave, all lanes active; ~6/wave avg,
//      requests unchanged). Results scatter back through LDS; ws store
//      stays coalesced. Predict phase A ~170-182us.
//
// Discrete steps (bottom_left trunc) replicated in float64 to match the
// NumPy reference under NEP-50 promotion. Resolutions hardcoded to the
// exact-math floor(16 * 2^(l/3)) values.

constexpr int NLEV = 16;
constexpr uint32_t HM_MASK = (1u << 19) - 1;

__device__ __constant__ double c_res[NLEV] = {
    16.0, 20.0, 25.0, 32.0, 40.0, 50.0, 64.0, 80.0,
    101.0, 128.0, 161.0, 203.0, 256.0, 322.0, 406.0, 512.0
};

// ---------------- Phase A: compacted per-level gather+interp ----------------
// One block = one level x 256 points. Requires B % 256 == 0 (guaranteed by
// launcher for this path, so no early-outs — block is barrier-uniform).
__global__ __launch_bounds__(256)
void ngp_levels_kernel(const float* __restrict__ x,
                       const float* __restrict__ table,
                       const float* __restrict__ box_min,
                       const float* __restrict__ box_max,
                       float2* __restrict__ ws,
                       int B, int chunks)
{
    __shared__ int s_cnt[4];
    __shared__ uint32_t s_h0[256], s_h1[256], s_h2[256];
    __shared__ float s_w0[256], s_w1[256], s_w2[256];
    __shared__ float s_f0[256], s_f1[256];

    // XCD-affinity: residue = blockIdx%8 -> XCD (HW round-robin dispatch).
    // XCD residue i: level i (phase 1, coarse) then 15-i (phase 2, fine).
    const int xcd = blockIdx.x & 7;
    const int s   = blockIdx.x >> 3;
    const int lev   = (s < chunks) ? xcd : (15 - xcd);
    const int chunk = (s < chunks) ? s : (s - chunks);
    const int t = threadIdx.x;
    const int b = chunk * 256 + t;

    // ---- prelude: exact-rounding f64 voxel math (UNCHANGED since R0) ----
    const float bm0 = box_min[0], bm1 = box_min[1], bm2 = box_min[2];
    const float d0 = box_max[0] - bm0;
    const float d1 = box_max[1] - bm1;
    const float d2 = box_max[2] - bm2;

    const float fx0 = x[3 * b + 0];
    const float fx1 = x[3 * b + 1];
    const float fx2 = x[3 * b + 2];

    const double res = c_res[lev];
    const double g0 = (double)d0 / res;
    const double g1 = (double)d1 / res;
    const double g2 = (double)d2 / res;
    const double q0 = (double)(fx0 - bm0) / g0;
    const double q1 = (double)(fx1 - bm1) / g1;
    const double q2 = (double)(fx2 - bm2) / g2;
    const int i0 = (int)q0;
    const int i1 = (int)q1;
    const int i2 = (int)q2;
    const float w0 = (float)(q0 - (double)i0);
    const float w1 = (float)(q1 - (double)i1);
    const float w2 = (float)(q2 - (double)i2);

    const uint32_t P1 = 2654435761u, P2 = 805459861u;
    const uint32_t h0 = (uint32_t)i0;
    const uint32_t h1 = (uint32_t)i1 * P1;
    const uint32_t h2 = (uint32_t)i2 * P2;

    // ---- parity compaction: slot = rank among evens / odds ----------------
    const int lane = t & 63;
    const int wv   = t >> 6;
    const bool evn = ((h0 & 1u) == 0u);
    const unsigned long long bal = __ballot(evn);
    const unsigned long long below = (lane == 63)
        ? (bal & ~(1ull << 63)) : (bal & ((1ull << (lane + 1)) - 1) >> 1);
    // simpler & branchless: bits strictly below `lane`
    const unsigned long long mlow = (1ull << lane) - 1ull;  // lane<64 safe: lane=63 -> all below
    const int lowerE = __popcll(bal & mlow);
    const int waveE  = __popcll(bal);
    (void)below;
    if (lane == 0) s_cnt[wv] = waveE;
    __syncthreads();

    int evenBase = 0, totalEven = 0;
#pragma unroll
    for (int i = 0; i < 4; ++i) {
        const int c = s_cnt[i];
        if (i < wv) evenBase += c;
        totalEven += c;
    }
    const int oddBase = totalEven + (wv * 64 - evenBase);
    const int slot = evn ? (evenBase + lowerE) : (oddBase + (lane - lowerE));

    s_h0[slot] = h0;  s_h1[slot] = h1;  s_h2[slot] = h2;
    s_w0[slot] = w0;  s_w1[slot] = w1;  s_w2[slot] = w2;
    __syncthreads();

    // ---- parity-uniform gather: slot t processes the point staged at t ----
    {
        const uint32_t H0 = s_h0[t];
        const uint32_t H1a = s_h1[t], H1b = H1a + P1;
        const uint32_t H2a = s_h2[t], H2b = H2a + P2;
        const float W0 = s_w0[t], W1 = s_w1[t], W2 = s_w2[t];
        const float U0 = 1.0f - W0, U1 = 1.0f - W1, U2 = 1.0f - W2;
        const float waa = U1 * U2;
        const float wab = U1 * W2;
        const float wba = W1 * U2;
        const float wbb = W1 * W2;
        const uint32_t base = (uint32_t)lev << 19;
        const float2* __restrict__ tab2 = (const float2*)table;

        float acc0, acc1;
        if (t < totalEven) {
            // even i0: x-corner pair {idx, idx^1} is one aligned float4.
            const float4* __restrict__ tab4 = (const float4*)table;
            acc0 = 0.0f; acc1 = 0.0f;
#define NGP_PAIR(HJK, WYZ)                                                    \
            {                                                                 \
                const uint32_t idx = (H0 ^ (HJK)) & HM_MASK;                  \
                const float4 q = tab4[(base + idx) >> 1];                     \
                const float wlo = (idx & 1u) ? W0 : U0;                       \
                const float whi = (idx & 1u) ? U0 : W0;                       \
                acc0 += (WYZ) * (wlo * q.x + whi * q.z);                      \
                acc1 += (WYZ) * (wlo * q.y + whi * q.w);                      \
            }
            NGP_PAIR(H1a ^ H2a, waa)
            NGP_PAIR(H1a ^ H2b, wab)
            NGP_PAIR(H1b ^ H2a, wba)
            NGP_PAIR(H1b ^ H2b, wbb)
#undef NGP_PAIR
        } else {
            // odd i0: 8x8B gather path.
            const uint32_t H0b = H0 + 1u;
            const float2 v000 = tab2[base + ((H0  ^ H1a ^ H2a) & HM_MASK)];
            const float2 v001 = tab2[base + ((H0  ^ H1a ^ H2b) & HM_MASK)];
            const float2 v010 = tab2[base + ((H0  ^ H1b ^ H2a) & HM_MASK)];
            const float2 v011 = tab2[base + ((H0  ^ H1b ^ H2b) & HM_MASK)];
            const float2 v100 = tab2[base + ((H0b ^ H1a ^ H2a) & HM_MASK)];
            const float2 v101 = tab2[base + ((H0b ^ H1a ^ H2b) & HM_MASK)];
            const float2 v110 = tab2[base + ((H0b ^ H1b ^ H2a) & HM_MASK)];
            const float2 v111 = tab2[base + ((H0b ^ H1b ^ H2b) & HM_MASK)];

            acc0 = U0 * (waa * v000.x + wab * v001.x + wba * v010.x + wbb * v011.x)
                 + W0 * (waa * v100.x + wab * v101.x + wba * v110.x + wbb * v111.x);
            acc1 = U0 * (waa * v000.y + wab * v001.y + wba * v010.y + wbb * v011.y)
                 + W0 * (waa * v100.y + wab * v101.y + wba * v110.y + wbb * v111.y);
        }
        s_f0[t] = acc0;
        s_f1[t] = acc1;
    }
    __syncthreads();

    // ---- scatter back to original order; coalesced 8B ws store ------------
    ws[(size_t)lev * B + b] = make_float2(s_f0[slot], s_f1[slot]);
}

// ---------------- Phase B: LDS tile transpose ws[l][b] -> out[b][f*16+l] ----
// Block = 256 points. Requires B % 256 == 0. TRUE COST ~33us ~= roofline
// (established R7); do not touch further.
// LDS layout: float rows indexed r = 2*l + f, row stride 257 floats (pad
// breaks the 32-point bank alias in stage 2). Size = 32*257*4 = 32896 B.
constexpr int LDS_STRIDE = 257;

__global__ __launch_bounds__(256)
void ngp_transpose_kernel(const float2* __restrict__ ws,
                          float* __restrict__ out,
                          int B)
{
    __shared__ float lds[32 * LDS_STRIDE];

    const int t  = threadIdx.x;
    const int P0 = blockIdx.x * 256;

    // Stage 1: coalesced level-row loads (512B per wave-instr) -> LDS.
    // Bank: ((2l*257 + t)) % 32 = (2l + t) % 32 -> 2 lanes/bank (free).
#pragma unroll
    for (int l = 0; l < NLEV; ++l) {
        const float2 v = ws[(size_t)l * B + P0 + t];
        lds[(2 * l)     * LDS_STRIDE + t] = v.x;
        lds[(2 * l + 1) * LDS_STRIDE + t] = v.y;
    }
    __syncthreads();

    // Stage 2: each store instr writes 1KB fully contiguous.
    // Lane t, iter j covers out flat range [P0*32 + j*1024 + 4t, +4):
    //   point p = j*32 + (t>>3), f = (t>>2)&1, l = (t&3)*4 + k.
    const int p_lo = t >> 3;
    const int f    = (t >> 2) & 1;
    const int l0   = (t & 3) * 4;
#pragma unroll
    for (int j = 0; j < 8; ++j) {
        const int p = j * 32 + p_lo;
        float4 v;
        v.x = lds[(2 * (l0 + 0) + f) * LDS_STRIDE + p];
        v.y = lds[(2 * (l0 + 1) + f) * LDS_STRIDE + p];
        v.z = lds[(2 * (l0 + 2) + f) * LDS_STRIDE + p];
        v.w = lds[(2 * (l0 + 3) + f) * LDS_STRIDE + p];
        *(float4*)(out + (size_t)P0 * 32 + j * 1024 + t * 4) = v;
    }
}

// ---------------- Fallback: fused kernel (if ws too small / B%256!=0) -------
__global__ __launch_bounds__(256)
void ngp_embed_fused_kernel(const float* __restrict__ x,
                            const float* __restrict__ table,
                            const float* __restrict__ box_min,
                            const float* __restrict__ box_max,
                            float* __restrict__ out,
                            int B)
{
    const int gid = blockIdx.x * 256 + threadIdx.x;
    const int b = gid >> 4;
    const int l = gid & 15;
    if (b >= B) return;

    const float bm0 = box_min[0], bm1 = box_min[1], bm2 = box_min[2];
    const float d0 = box_max[0] - bm0;
    const float d1 = box_max[1] - bm1;
    const float d2 = box_max[2] - bm2;

    const float fx0 = x[3 * b + 0];
    const float fx1 = x[3 * b + 1];
    const float fx2 = x[3 * b + 2];

    const double res = c_res[l];
    const double q0 = (double)(fx0 - bm0) / ((double)d0 / res);
    const double q1 = (double)(fx1 - bm1) / ((double)d1 / res);
    const double q2 = (double)(fx2 - bm2) / ((double)d2 / res);
    const int i0 = (int)q0;
    const int i1 = (int)q1;
    const int i2 = (int)q2;
    const float w0 = (float)(q0 - (double)i0);
    const float w1 = (float)(q1 - (double)i1);
    const float w2 = (float)(q2 - (double)i2);

    const uint32_t P1 = 2654435761u, P2 = 805459861u;
    const uint32_t h0a = (uint32_t)i0;
    const uint32_t h0b = h0a + 1u;
    const uint32_t h1a = (uint32_t)i1 * P1;
    const uint32_t h1b = h1a + P1;
    const uint32_t h2a = (uint32_t)i2 * P2;
    const uint32_t h2b = h2a + P2;
    const uint32_t base = (uint32_t)l << 19;
    const float2* __restrict__ tab2 = (const float2*)table;

    const float2 v000 = tab2[base + ((h0a ^ h1a ^ h2a) & HM_MASK)];
    const float2 v001 = tab2[base + ((h0a ^ h1a ^ h2b) & HM_MASK)];
    const float2 v010 = tab2[base + ((h0a ^ h1b ^ h2a) & HM_MASK)];
    const float2 v011 = tab2[base + ((h0a ^ h1b ^ h2b) & HM_MASK)];
    const float2 v100 = tab2[base + ((h0b ^ h1a ^ h2a) & HM_MASK)];
    const float2 v101 = tab2[base + ((h0b ^ h1a ^ h2b) & HM_MASK)];
    const float2 v110 = tab2[base + ((h0b ^ h1b ^ h2a) & HM_MASK)];
    const float2 v111 = tab2[base + ((h0b ^ h1b ^ h2b) & HM_MASK)];

    const float u0 = 1.0f - w0, u1 = 1.0f - w1, u2 = 1.0f - w2;
    const float waa = u1 * u2;
    const float wab = u1 * w2;
    const float wba = w1 * u2;
    const float wbb = w1 * w2;

    const float f0 = u0 * (waa * v000.x + wab * v001.x + wba * v010.x + wbb * v011.x)
                   + w0 * (waa * v100.x + wab * v101.x + wba * v110.x + wbb * v111.x);
    const float f1 = u0 * (waa * v000.y + wab * v001.y + wba * v010.y + wbb * v011.y)
                   + w0 * (waa * v100.y + wab * v101.y + wba * v110.y + wbb * v111.y);

    out[b * 32 + l]      = f0;
    out[b * 32 + 16 + l] = f1;
}

extern "C" void kernel_launch(void* const* d_in, const int* in_sizes, int n_in,
                              void* d_out, int out_size, void* d_ws, size_t ws_size,
                              hipStream_t stream) {
    const float* x       = (const float*)d_in[0];
    const float* table   = (const float*)d_in[1];
    const float* box_min = (const float*)d_in[2];
    const float* box_max = (const float*)d_in[3];
    float* out = (float*)d_out;

    const int B = in_sizes[0] / 3;
    const size_t ws_needed = (size_t)B * NLEV * sizeof(float2);

    if (ws_size >= ws_needed && (B % 256) == 0) {
        const int chunks = B / 256;               // per level, 256 pts/block
        const int gridA = 8 * 2 * chunks;         // 8 residues x 2 levels
        hipLaunchKernelGGL(ngp_levels_kernel, dim3(gridA), dim3(256), 0, stream,
                           x, table, box_min, box_max, (float2*)d_ws, B, chunks);
        const int gridB = B / 256;
        hipLaunchKernelGGL(ngp_transpose_kernel, dim3(gridB), dim3(256), 0, stream,
                           (const float2*)d_ws, out, B);
    } else {
        const int total = B * NLEV;
        const int blocks = (total + 255) / 256;
        hipLaunchKernelGGL(ngp_embed_fused_kernel, dim3(blocks), dim3(256), 0, stream,
                           x, table, box_min, box_max, out, B);
    }
}

// Round 6
// 315.710 us; speedup vs baseline: 1.0162x; 1.0162x over previous
//
#include <hip/hip_runtime.h>
#include <cstdint>

// Instant-NGP hash-grid embedder, 2-phase with level->XCD affinity.
//
// Journal:
//  R2: level->XCD affinity (blockIdx%8 pins level pairs (i,15-i)); FETCH
//      1.56GB -> 149MB. Phase A ~= per-XCD L2 request roofline (218us model).
//  R4: no __builtin_nontemporal_* (regressed both phases).
//  R5/R6: phase-B store/read pattern rewrites: NEUTRAL (phase B ~33us
//      ~= its 128MB roofline; established via R7's overhead measurement:
//      harness adds ~78us/iter that no kernel sees). Phase B is DONE.
//  R7: fused tail transpose + sc1: FAILED (write-through doubled WRITE).
//  R8: parity-paired x-corners (x prime = 1 -> idx(i0+1)=idx(i0)^1, even i0
//      -> one aligned float4). L2 requests -25%, phase A 225->199us.
//  R9: parity COMPACTION (uniform gather waves via LDS ballot/scan): FAILED
//      199->209us. Per-wave VMEM instruction count is NOT a resource;
//      divergent R8 form gathers equally fast. Reverted.
//      => post-R8 floor ~199us is NOT L2-request-bound (82% of port) and NOT
//      instruction-count-bound. Candidates: per-CU gather return path
//      (returned bytes identical across R8 paths: 64B/point either way),
//      or VALU-issue/latency from the f64 prelude (6 f64 divides/pt-lvl).
//  R10: F32 PRELUDE (this — resubmitted verbatim after an infra-only bench
//      failure: "MI355X container failed twice", no kernel signal).
//      Trilinear interp with w = q - trunc(q) from the SAME q is CONTINUOUS
//      in q (at q=k, (i=k-1,w~1) and (i=k,w=0) both give v(k)), so f32
//      rounding of q (<=3e-5 abs at q<=512) perturbs the OUTPUT by
//      ~gradient*dq ~ 2e-8 << absmax 4.8e-7. Boundary-exact i is
//      unnecessary. Kills all f64: ~half the per-wave issue + most of the
//      pre-gather latency chain. If neutral -> floor is the gather return
//      path (memory-side, structural).
//
// Resolutions hardcoded to the exact-math floor(16 * 2^(l/3)) values.

constexpr int NLEV = 16;
constexpr uint32_t HM_MASK = (1u << 19) - 1;

__device__ __constant__ float c_resf[NLEV] = {
    16.0f, 20.0f, 25.0f, 32.0f, 40.0f, 50.0f, 64.0f, 80.0f,
    101.0f, 128.0f, 161.0f, 203.0f, 256.0f, 322.0f, 406.0f, 512.0f
};

__device__ __forceinline__ void ngp_eval_point(
    int b, int lev,
    const float* __restrict__ x,
    const float* __restrict__ table,
    float bm0, float bm1, float bm2,
    float d0, float d1, float d2,
    float& f0, float& f1)
{
    const float fx0 = x[3 * b + 0];
    const float fx1 = x[3 * b + 1];
    const float fx2 = x[3 * b + 2];

    // f32 prelude (R10): q = (x-bm) * (res/d); i = trunc(q); w = q - i.
    // One f32 divide per dim (block-uniform value), then FMA-class ops.
    const float resf = c_resf[lev];
    const float s0 = resf / d0;
    const float s1 = resf / d1;
    const float s2 = resf / d2;
    const float q0 = (fx0 - bm0) * s0;
    const float q1 = (fx1 - bm1) * s1;
    const float q2 = (fx2 - bm2) * s2;
    const int i0 = (int)q0;
    const int i1 = (int)q1;
    const int i2 = (int)q2;
    const float w0 = q0 - (float)i0;
    const float w1 = q1 - (float)i1;
    const float w2 = q2 - (float)i2;

    const uint32_t P1 = 2654435761u, P2 = 805459861u;
    const uint32_t h0a = (uint32_t)i0;
    const uint32_t h1a = (uint32_t)i1 * P1;
    const uint32_t h1b = h1a + P1;
    const uint32_t h2a = (uint32_t)i2 * P2;
    const uint32_t h2b = h2a + P2;
    const uint32_t base = (uint32_t)lev << 19;
    const float2* __restrict__ tab2 = (const float2*)table;

    const float u0 = 1.0f - w0, u1 = 1.0f - w1, u2 = 1.0f - w2;
    const float waa = u1 * u2;
    const float wab = u1 * w2;
    const float wba = w1 * u2;
    const float wbb = w1 * w2;

    float acc0 = 0.0f, acc1 = 0.0f;

    if ((h0a & 1u) == 0u) {
        // ---- even i0 (R8): x-corner pair {idx, idx^1} is one aligned
        // float4 (x hash prime = 1). 4 requests instead of 8.
        const float4* __restrict__ tab4 = (const float4*)table;
#define NGP_PAIR(HJK, WYZ)                                                    \
        {                                                                     \
            const uint32_t idx = (h0a ^ (HJK)) & HM_MASK;                     \
            const float4 q = tab4[(base + idx) >> 1];                         \
            const float wlo = (idx & 1u) ? w0 : u0;                           \
            const float whi = (idx & 1u) ? u0 : w0;                           \
            acc0 += (WYZ) * (wlo * q.x + whi * q.z);                          \
            acc1 += (WYZ) * (wlo * q.y + whi * q.w);                          \
        }
        NGP_PAIR(h1a ^ h2a, waa)
        NGP_PAIR(h1a ^ h2b, wab)
        NGP_PAIR(h1b ^ h2a, wba)
        NGP_PAIR(h1b ^ h2b, wbb)
#undef NGP_PAIR
    } else {
        // ---- odd i0: original 8x8B gather path --------------------------
        const uint32_t h0b = h0a + 1u;
        const float2 v000 = tab2[base + ((h0a ^ h1a ^ h2a) & HM_MASK)];
        const float2 v001 = tab2[base + ((h0a ^ h1a ^ h2b) & HM_MASK)];
        const float2 v010 = tab2[base + ((h0a ^ h1b ^ h2a) & HM_MASK)];
        const float2 v011 = tab2[base + ((h0a ^ h1b ^ h2b) & HM_MASK)];
        const float2 v100 = tab2[base + ((h0b ^ h1a ^ h2a) & HM_MASK)];
        const float2 v101 = tab2[base + ((h0b ^ h1a ^ h2b) & HM_MASK)];
        const float2 v110 = tab2[base + ((h0b ^ h1b ^ h2a) & HM_MASK)];
        const float2 v111 = tab2[base + ((h0b ^ h1b ^ h2b) & HM_MASK)];

        acc0 = u0 * (waa * v000.x + wab * v001.x + wba * v010.x + wbb * v011.x)
             + w0 * (waa * v100.x + wab * v101.x + wba * v110.x + wbb * v111.x);
        acc1 = u0 * (waa * v000.y + wab * v001.y + wba * v010.y + wbb * v011.y)
             + w0 * (waa * v100.y + wab * v101.y + wba * v110.y + wbb * v111.y);
    }

    f0 = acc0;
    f1 = acc1;
}

// ---------------- Phase A: per-level gather+interp, level-major ws ----------
// EXACT R2/R8 structure; no LDS, no compaction (R9 lesson).
__global__ __launch_bounds__(256)
void ngp_levels_kernel(const float* __restrict__ x,
                       const float* __restrict__ table,
                       const float* __restrict__ box_min,
                       const float* __restrict__ box_max,
                       float2* __restrict__ ws,
                       int B, int chunks)
{
    // XCD-affinity: residue = blockIdx%8 -> XCD (HW round-robin dispatch).
    // XCD residue i: level i (phase 1, coarse) then 15-i (phase 2, fine).
    const int xcd = blockIdx.x & 7;
    const int s   = blockIdx.x >> 3;
    const int lev   = (s < chunks) ? xcd : (15 - xcd);
    const int chunk = (s < chunks) ? s : (s - chunks);
    const int b = chunk * 256 + threadIdx.x;
    if (b >= B) return;

    const float bm0 = box_min[0], bm1 = box_min[1], bm2 = box_min[2];
    const float d0 = box_max[0] - bm0;
    const float d1 = box_max[1] - bm1;
    const float d2 = box_max[2] - bm2;

    float f0, f1;
    ngp_eval_point(b, lev, x, table,
                   bm0, bm1, bm2, d0, d1, d2, f0, f1);

    ws[(size_t)lev * B + b] = make_float2(f0, f1);  // coalesced 8B
}

// ---------------- Phase B: LDS tile transpose ws[l][b] -> out[b][f*16+l] ----
// Block = 256 points. Requires B % 256 == 0. TRUE COST ~33us ~= roofline
// (established R7); do not touch further.
// LDS layout: float rows indexed r = 2*l + f, row stride 257 floats (pad
// breaks the 32-point bank alias in stage 2). Size = 32*257*4 = 32896 B.
constexpr int LDS_STRIDE = 257;

__global__ __launch_bounds__(256)
void ngp_transpose_kernel(const float2* __restrict__ ws,
                          float* __restrict__ out,
                          int B)
{
    __shared__ float lds[32 * LDS_STRIDE];

    const int t  = threadIdx.x;
    const int P0 = blockIdx.x * 256;

    // Stage 1: coalesced level-row loads (512B per wave-instr) -> LDS.
    // Bank: ((2l*257 + t)) % 32 = (2l + t) % 32 -> 2 lanes/bank (free).
#pragma unroll
    for (int l = 0; l < NLEV; ++l) {
        const float2 v = ws[(size_t)l * B + P0 + t];
        lds[(2 * l)     * LDS_STRIDE + t] = v.x;
        lds[(2 * l + 1) * LDS_STRIDE + t] = v.y;
    }
    __syncthreads();

    // Stage 2: each store instr writes 1KB fully contiguous.
    // Lane t, iter j covers out flat range [P0*32 + j*1024 + 4t, +4):
    //   point p = j*32 + (t>>3), f = (t>>2)&1, l = (t&3)*4 + k.
    const int p_lo = t >> 3;
    const int f    = (t >> 2) & 1;
    const int l0   = (t & 3) * 4;
#pragma unroll
    for (int j = 0; j < 8; ++j) {
        const int p = j * 32 + p_lo;
        float4 v;
        v.x = lds[(2 * (l0 + 0) + f) * LDS_STRIDE + p];
        v.y = lds[(2 * (l0 + 1) + f) * LDS_STRIDE + p];
        v.z = lds[(2 * (l0 + 2) + f) * LDS_STRIDE + p];
        v.w = lds[(2 * (l0 + 3) + f) * LDS_STRIDE + p];
        *(float4*)(out + (size_t)P0 * 32 + j * 1024 + t * 4) = v;
    }
}

// ---------------- Fallback: fused kernel (if ws too small / B%256!=0) -------
__global__ __launch_bounds__(256)
void ngp_embed_fused_kernel(const float* __restrict__ x,
                            const float* __restrict__ table,
                            const float* __restrict__ box_min,
                            const float* __restrict__ box_max,
                            float* __restrict__ out,
                            int B)
{
    const int gid = blockIdx.x * 256 + threadIdx.x;
    const int b = gid >> 4;
    const int l = gid & 15;
    if (b >= B) return;

    const float bm0 = box_min[0], bm1 = box_min[1], bm2 = box_min[2];
    const float d0 = box_max[0] - bm0;
    const float d1 = box_max[1] - bm1;
    const float d2 = box_max[2] - bm2;

    float f0, f1;
    ngp_eval_point(b, l, x, table,
                   bm0, bm1, bm2, d0, d1, d2, f0, f1);

    out[b * 32 + l]      = f0;
    out[b * 32 + 16 + l] = f1;
}

extern "C" void kernel_launch(void* const* d_in, const int* in_sizes, int n_in,
                              void* d_out, int out_size, void* d_ws, size_t ws_size,
                              hipStream_t stream) {
    const float* x       = (const float*)d_in[0];
    const float* table   = (const float*)d_in[1];
    const float* box_min = (const float*)d_in[2];
    const float* box_max = (const float*)d_in[3];
    float* out = (float*)d_out;

    const int B = in_sizes[0] / 3;
    const size_t ws_needed = (size_t)B * NLEV * sizeof(float2);

    if (ws_size >= ws_needed && (B % 256) == 0) {
        const int chunks = B / 256;               // per level, 256 pts/block
        const int gridA = 8 * 2 * chunks;         // 8 residues x 2 levels
        hipLaunchKernelGGL(ngp_levels_kernel, dim3(gridA), dim3(256), 0, stream,
                           x, table, box_min, box_max, (float2*)d_ws, B, chunks);
        const int gridB = B / 256;
        hipLaunchKernelGGL(ngp_transpose_kernel, dim3(gridB), dim3(256), 0, stream,
                           (const float2*)d_ws, out, B);
    } else {
        const int total = B * NLEV;
        const int blocks = (total + 255) / 256;
        hipLaunchKernelGGL(ngp_embed_fused_kernel, dim3(blocks), dim3(256), 0, stream,
                           x, table, box_min, box_max, out, B);
    }
}